// Round 1
// baseline (923.790 us; speedup 1.0000x reference)
//
#include <hip/hip_runtime.h>
#include <hip/hip_bf16.h>
#include <math.h>

#define B_N   512
#define D_N   768
#define R_N   128
#define C_NEW 10
#define C_OLD 100
#define C_TOT 110
#define BT    64
#define DC    32
#define NCHUNK (D_N / DC)
#define MARGIN_F   5.0f
#define VAR_FLOOR_F 1e-4f
#define BIG_F  1e6f

__device__ __forceinline__ float cleanf(float v) {
    return isfinite(v) ? v : 0.0f;
}

// dist[b, c] for one class c and a 64-row batch tile.
__global__ __launch_bounds__(256)
void dist_kernel(const float* __restrict__ z,
                 const float* __restrict__ cur_means, const float* __restrict__ cur_bases,
                 const float* __restrict__ cur_vars,
                 const float* __restrict__ old_means, const float* __restrict__ old_bases,
                 const float* __restrict__ old_vars,
                 float* __restrict__ gdist)
{
    const int b0 = blockIdx.x * BT;
    const int c  = blockIdx.y;
    const float* means; const float* bases; const float* vars;
    if (c < C_NEW) {
        means = cur_means + (size_t)c * D_N;
        bases = cur_bases + (size_t)c * D_N * R_N;
        vars  = cur_vars  + (size_t)c * (R_N + 1);
    } else {
        int co = c - C_NEW;
        means = old_means + (size_t)co * D_N;
        bases = old_bases + (size_t)co * D_N * R_N;
        vars  = old_vars  + (size_t)co * (R_N + 1);
    }

    __shared__ float sCoef[BT][R_N + 4];   // stride 132: 16B-aligned rows, bank-spread
    __shared__ float sZ[BT][DC + 1];
    __shared__ float sB[DC][R_N + 4];
    __shared__ float sEig[R_N];
    __shared__ float sRed[BT][4];
    __shared__ float sPar[BT];

    const int tid = threadIdx.x;
    if (tid < R_N) sEig[tid] = fmaxf(vars[tid], VAR_FLOOR_F);

    // ---------------- Phase A: coeff[b][r] = sum_d diff[b][d] * B[d][r] ----------------
    const int tb = tid >> 4;   // 0..15 -> 4 batch rows each
    const int tr = tid & 15;   // 0..15 -> 8 r-cols each
    float acc[4][8];
    #pragma unroll
    for (int i = 0; i < 4; ++i)
        #pragma unroll
        for (int j = 0; j < 8; ++j) acc[i][j] = 0.f;

    for (int ch = 0; ch < NCHUNK; ++ch) {
        const int d0 = ch * DC;
        __syncthreads();
        for (int e = tid; e < BT * DC; e += 256) {
            int b = e >> 5, dd = e & 31;
            float zv = cleanf(z[(size_t)(b0 + b) * D_N + d0 + dd]);
            sZ[b][dd] = zv - means[d0 + dd];
        }
        for (int e = tid; e < DC * R_N; e += 256) {
            int dd = e >> 7, r = e & 127;
            sB[dd][r] = bases[(size_t)(d0 + dd) * R_N + r];
        }
        __syncthreads();
        #pragma unroll 8
        for (int dd = 0; dd < DC; ++dd) {
            float zr[4];
            #pragma unroll
            for (int i = 0; i < 4; ++i) zr[i] = sZ[tb * 4 + i][dd];
            float4 bv0 = *(const float4*)&sB[dd][tr * 8];
            float4 bv1 = *(const float4*)&sB[dd][tr * 8 + 4];
            float br[8] = {bv0.x, bv0.y, bv0.z, bv0.w, bv1.x, bv1.y, bv1.z, bv1.w};
            #pragma unroll
            for (int i = 0; i < 4; ++i)
                #pragma unroll
                for (int j = 0; j < 8; ++j) acc[i][j] += zr[i] * br[j];
        }
    }
    #pragma unroll
    for (int i = 0; i < 4; ++i) {
        *(float4*)&sCoef[tb * 4 + i][tr * 8]     = make_float4(acc[i][0], acc[i][1], acc[i][2], acc[i][3]);
        *(float4*)&sCoef[tb * 4 + i][tr * 8 + 4] = make_float4(acc[i][4], acc[i][5], acc[i][6], acc[i][7]);
    }
    __syncthreads();

    // ---------------- Phase C: parallel[b] = sum_r coeff^2 / eig ----------------
    const int bb = tid >> 2;   // 0..63
    const int q  = tid & 3;    // 0..3
    {
        float par = 0.f;
        #pragma unroll 8
        for (int k = 0; k < 32; ++k) {
            float cv = sCoef[bb][q * 32 + k];
            par += cv * cv / sEig[q * 32 + k];
        }
        sRed[bb][q] = par;
    }
    __syncthreads();
    if (tid < BT) sPar[tid] = sRed[tid][0] + sRed[tid][1] + sRed[tid][2] + sRed[tid][3];
    __syncthreads();

    // ---------------- Phase D: residual[b] = sum_d (diff - recon)^2 ----------------
    float rsd = 0.f;
    for (int ch = 0; ch < NCHUNK; ++ch) {
        const int d0 = ch * DC;
        __syncthreads();
        for (int e = tid; e < BT * DC; e += 256) {
            int b = e >> 5, dd = e & 31;
            float zv = cleanf(z[(size_t)(b0 + b) * D_N + d0 + dd]);
            sZ[b][dd] = zv - means[d0 + dd];
        }
        for (int e = tid; e < DC * R_N; e += 256) {
            int dd = e >> 7, r = e & 127;
            sB[dd][r] = bases[(size_t)(d0 + dd) * R_N + r];
        }
        __syncthreads();
        float rec[8];
        #pragma unroll
        for (int d8 = 0; d8 < 8; ++d8) rec[d8] = 0.f;
        #pragma unroll 4
        for (int r4 = 0; r4 < R_N; r4 += 4) {
            float4 cf = *(const float4*)&sCoef[bb][r4];
            #pragma unroll
            for (int d8 = 0; d8 < 8; ++d8) {
                float4 bv = *(const float4*)&sB[q * 8 + d8][r4];
                rec[d8] += cf.x * bv.x + cf.y * bv.y + cf.z * bv.z + cf.w * bv.w;
            }
        }
        #pragma unroll
        for (int d8 = 0; d8 < 8; ++d8) {
            float df = sZ[bb][q * 8 + d8] - rec[d8];
            rsd += df * df;
        }
    }
    __syncthreads();
    sRed[bb][q] = rsd;
    __syncthreads();
    if (tid < BT) {
        float res = fmaxf(vars[R_N], VAR_FLOOR_F);
        float residual = (sRed[tid][0] + sRed[tid][1] + sRed[tid][2] + sRed[tid][3]) / res;
        float dist = (sPar[tid] + residual) / (float)D_N;
        if (!isfinite(dist)) dist = BIG_F;
        gdist[(size_t)(b0 + tid) * C_TOT + c] = dist;
    }
}

// Final reduction: old_min, per-class masked means, hinge, valid-averaging.
__global__ __launch_bounds__(256)
void finalize_kernel(const float* __restrict__ gdist,
                     const int* __restrict__ labels,
                     const int* __restrict__ ncid,
                     float* __restrict__ out)
{
    __shared__ float sOldMin[B_N];
    __shared__ float sCnt[C_NEW], sTot[C_NEW], sOwn[C_NEW], sOld[C_NEW];
    const int tid = threadIdx.x;
    if (tid < C_NEW) { sCnt[tid] = 0.f; sTot[tid] = 0.f; sOwn[tid] = 0.f; sOld[tid] = 0.f; }
    __syncthreads();
    for (int b = tid; b < B_N; b += 256) {
        float mn = 3.4e38f;
        const float* row = gdist + (size_t)b * C_TOT;
        for (int cc = C_NEW; cc < C_TOT; ++cc) mn = fminf(mn, row[cc]);
        sOldMin[b] = mn;
    }
    __syncthreads();
    for (int b = tid; b < B_N; b += 256) {
        int lab = labels[b];
        float om = sOldMin[b];
        for (int k = 0; k < C_NEW; ++k) {
            if (lab == ncid[k]) {
                int col = ncid[k];
                col = min(max(col, 0), C_TOT - 1);
                float ow = gdist[(size_t)b * C_TOT + col];
                atomicAdd(&sCnt[k], 1.0f);
                atomicAdd(&sTot[k], fmaxf(0.0f, MARGIN_F + ow - om));
                atomicAdd(&sOwn[k], ow);
                atomicAdd(&sOld[k], om);
            }
        }
    }
    __syncthreads();
    if (tid == 0) {
        float total = 0.f, own = 0.f, old = 0.f, nv = 0.f;
        for (int k = 0; k < C_NEW; ++k) {
            float cnt = sCnt[k];
            float den = fmaxf(cnt, 1.0f);
            if (cnt > 0.f) {
                nv += 1.f;
                total += sTot[k] / den;
                own   += sOwn[k] / den;
                old   += sOld[k] / den;
            }
        }
        float nvd = fmaxf(nv, 1.0f);
        out[0] = total / nvd;
        out[1] = own / nvd;
        out[2] = old / nvd;
    }
}

extern "C" void kernel_launch(void* const* d_in, const int* in_sizes, int n_in,
                              void* d_out, int out_size, void* d_ws, size_t ws_size,
                              hipStream_t stream)
{
    const float* features  = (const float*)d_in[0];
    const int*   labels    = (const int*)d_in[1];
    const int*   ncid      = (const int*)d_in[2];
    const float* cur_means = (const float*)d_in[3];
    const float* cur_bases = (const float*)d_in[4];
    const float* cur_vars  = (const float*)d_in[5];
    const float* old_means = (const float*)d_in[6];
    const float* old_bases = (const float*)d_in[7];
    const float* old_vars  = (const float*)d_in[8];

    float* gdist = (float*)d_ws;   // [B_N][C_TOT] = 225 KB

    dim3 grid(B_N / BT, C_TOT);
    dist_kernel<<<grid, dim3(256), 0, stream>>>(features,
                                                cur_means, cur_bases, cur_vars,
                                                old_means, old_bases, old_vars,
                                                gdist);
    finalize_kernel<<<1, dim3(256), 0, stream>>>(gdist, labels, ncid, (float*)d_out);
}

// Round 2
// 267.459 us; speedup vs baseline: 3.4540x; 3.4540x over previous
//
#include <hip/hip_runtime.h>
#include <hip/hip_bf16.h>
#include <math.h>
#include <stdint.h>

#define B_N   512
#define D_N   768
#define R_N   128
#define C_NEW 10
#define C_OLD 100
#define C_TOT 110
#define MARGIN_F    5.0f
#define VAR_FLOOR_F 1e-4f
#define BIG_F       1e6f

typedef __bf16 bf16;
typedef __bf16 bf16x8 __attribute__((ext_vector_type(8)));
typedef float  f32x4  __attribute__((ext_vector_type(4)));

__device__ __forceinline__ float cleanf(float v) { return isfinite(v) ? v : 0.0f; }

// ---------------------------------------------------------------------------
// prep_z: clean z -> bf16 copy, znorm[b], zdotmu[b][c]. grid 128, block 256.
// wave w handles row b = blockIdx.x*4 + w.
// ---------------------------------------------------------------------------
__global__ __launch_bounds__(256)
void prep_z(const float* __restrict__ z,
            const float* __restrict__ cur_means, const float* __restrict__ old_means,
            bf16* __restrict__ zbf, float* __restrict__ znorm, float* __restrict__ zdotmu)
{
    const int wave = threadIdx.x >> 6, lane = threadIdx.x & 63;
    const int b = blockIdx.x * 4 + wave;
    float zr[12];
    #pragma unroll
    for (int i = 0; i < 12; ++i) {
        float v = cleanf(z[b * D_N + i * 64 + lane]);
        zr[i] = v;
        zbf[b * D_N + i * 64 + lane] = (bf16)v;
    }
    float nrm = 0.f;
    #pragma unroll
    for (int i = 0; i < 12; ++i) nrm += zr[i] * zr[i];
    #pragma unroll
    for (int off = 32; off >= 1; off >>= 1) nrm += __shfl_xor(nrm, off, 64);
    if (lane == 0) znorm[b] = nrm;

    for (int c = 0; c < C_TOT; ++c) {
        const float* mu = (c < C_NEW) ? cur_means + (size_t)c * D_N
                                      : old_means + (size_t)(c - C_NEW) * D_N;
        float p = 0.f;
        #pragma unroll
        for (int i = 0; i < 12; ++i) p += zr[i] * mu[i * 64 + lane];
        #pragma unroll
        for (int off = 32; off >= 1; off >>= 1) p += __shfl_xor(p, off, 64);
        if (lane == 0) zdotmu[b * C_TOT + c] = p;
    }
}

// ---------------------------------------------------------------------------
// prep_munorm: munorm[c] = ||mu_c||^2. grid 110, block 256.
// ---------------------------------------------------------------------------
__global__ __launch_bounds__(256)
void prep_munorm(const float* __restrict__ cur_means, const float* __restrict__ old_means,
                 float* __restrict__ munorm)
{
    const int c = blockIdx.x;
    const float* mu = (c < C_NEW) ? cur_means + (size_t)c * D_N
                                  : old_means + (size_t)(c - C_NEW) * D_N;
    float p = 0.f;
    for (int d = threadIdx.x; d < D_N; d += 256) p += mu[d] * mu[d];
    #pragma unroll
    for (int off = 32; off >= 1; off >>= 1) p += __shfl_xor(p, off, 64);
    __shared__ float s[4];
    const int wave = threadIdx.x >> 6, lane = threadIdx.x & 63;
    if (lane == 0) s[wave] = p;
    __syncthreads();
    if (threadIdx.x == 0) munorm[c] = s[0] + s[1] + s[2] + s[3];
}

// ---------------------------------------------------------------------------
// transpose_mc: basesT[c][r][d] (bf16) from bases[c][d][r] (f32), plus
// m_c[c][r] += sum_d mu[d]*B[d][r] (atomic, m_c pre-zeroed).
// grid (6, 110), block 256. Tile: 128 d x 128 r.
// ---------------------------------------------------------------------------
__global__ __launch_bounds__(256)
void transpose_mc(const float* __restrict__ cur_bases, const float* __restrict__ old_bases,
                  const float* __restrict__ cur_means, const float* __restrict__ old_means,
                  bf16* __restrict__ basesT, float* __restrict__ m_c)
{
    const int dt = blockIdx.x, c = blockIdx.y;
    const float* Bc = (c < C_NEW) ? cur_bases + (size_t)c * D_N * R_N
                                  : old_bases + (size_t)(c - C_NEW) * D_N * R_N;
    const float* mu = (c < C_NEW) ? cur_means + (size_t)c * D_N
                                  : old_means + (size_t)(c - C_NEW) * D_N;
    __shared__ bf16 T[128][132];   // [r][d], stride 132 (264B: 8B-aligned quads, spread banks)
    __shared__ float sMu[128];
    const int t = threadIdx.x;
    const int d0 = dt * 128;
    if (t < 128) sMu[t] = mu[d0 + t];

    // load f32 tile (coalesced along r), write bf16 transposed to LDS
    #pragma unroll 4
    for (int it = 0; it < 16; ++it) {
        int q = it * 256 + t;            // 4096 float4
        int d = q >> 5, rr = (q & 31) * 4;
        float4 v = *(const float4*)(Bc + (size_t)(d0 + d) * R_N + rr);
        T[rr + 0][d] = (bf16)v.x;
        T[rr + 1][d] = (bf16)v.y;
        T[rr + 2][d] = (bf16)v.z;
        T[rr + 3][d] = (bf16)v.w;
    }
    __syncthreads();

    // write out coalesced along d (8B per lane)
    #pragma unroll 4
    for (int it = 0; it < 16; ++it) {
        int q = it * 256 + t;
        int r = q >> 5, dd = (q & 31) * 4;
        ushort4 w = *(const ushort4*)&T[r][dd];
        *(ushort4*)(basesT + (size_t)c * R_N * D_N + (size_t)r * D_N + d0 + dd) = w;
    }

    // m_c partial from the LDS tile
    {
        int r = t & 127, dh = t >> 7;
        float p = 0.f;
        #pragma unroll 8
        for (int k = 0; k < 64; ++k) {
            int d = dh * 64 + k;
            p += sMu[d] * (float)T[r][d];
        }
        atomicAdd(&m_c[c * R_N + r], p);
    }
}

// ---------------------------------------------------------------------------
// gram: G[c] = B_c^T B_c in bf16 from basesT (NT MFMA GEMM, 128x128, K=768).
// grid 110, block 256 (4 waves, each 64x64 subtile).
// ---------------------------------------------------------------------------
__global__ __launch_bounds__(256)
void gram(const bf16* __restrict__ basesT, bf16* __restrict__ G)
{
    const int c = blockIdx.x;
    const bf16* Tc = basesT + (size_t)c * R_N * D_N;
    __shared__ bf16 sT[128][72];
    const int tid = threadIdx.x, wave = tid >> 6, lane = tid & 63;
    const int quad = lane >> 4, l15 = lane & 15;
    const int wr = (wave >> 1) * 64, wc = (wave & 1) * 64;

    f32x4 acc[4][4];
    #pragma unroll
    for (int i = 0; i < 4; ++i)
        #pragma unroll
        for (int j = 0; j < 4; ++j) acc[i][j] = (f32x4)0.0f;

    for (int k0 = 0; k0 < D_N; k0 += 64) {
        __syncthreads();
        #pragma unroll
        for (int p = 0; p < 4; ++p) {
            int q = p * 256 + tid, row = q >> 3, u = q & 7;
            *(uint4*)(&sT[row][u * 8]) = *(const uint4*)(Tc + (size_t)row * D_N + k0 + u * 8);
        }
        __syncthreads();
        #pragma unroll
        for (int kk = 0; kk < 64; kk += 32) {
            bf16x8 af[4], bg[4];
            #pragma unroll
            for (int i = 0; i < 4; ++i) af[i] = *(const bf16x8*)(&sT[wr + 16 * i + l15][kk + quad * 8]);
            #pragma unroll
            for (int j = 0; j < 4; ++j) bg[j] = *(const bf16x8*)(&sT[wc + 16 * j + l15][kk + quad * 8]);
            #pragma unroll
            for (int i = 0; i < 4; ++i)
                #pragma unroll
                for (int j = 0; j < 4; ++j)
                    acc[i][j] = __builtin_amdgcn_mfma_f32_16x16x32_bf16(af[i], bg[j], acc[i][j], 0, 0, 0);
        }
    }
    #pragma unroll
    for (int i = 0; i < 4; ++i)
        #pragma unroll
        for (int j = 0; j < 4; ++j)
            #pragma unroll
            for (int reg = 0; reg < 4; ++reg) {
                int r = wr + 16 * i + quad * 4 + reg;
                int s = wc + 16 * j + l15;
                G[(size_t)c * 16384 + (size_t)r * 128 + s] = (bf16)acc[i][j][reg];
            }
}

// ---------------------------------------------------------------------------
// main_dist: per (mtile, class): coeff = z*B - m_c (MFMA), par/cnorm,
// H = coeff*G (MFMA), qsum, dist. grid (4, 110), block 256.
// ---------------------------------------------------------------------------
#define PADC 136
#define SM_A   0                      // sA [128][72] bf16 = 18432
#define SM_B   18432                  // sB [128][72] bf16 = 18432
#define SM_G   0                      // sG [128][136] bf16 = 34816 (reuses A/B)
#define SM_C   36864                  // sC [128][136] bf16 = 34816
#define SM_M   (36864 + 34816)        // sM   128 f32
#define SM_INV (SM_M + 512)           // sInv 128 f32
#define SM_PAR (SM_INV + 512)         // sPar 128 f32
#define SM_CN  (SM_PAR + 512)         // sCn  128 f32
#define SM_Q   (SM_CN + 512)          // sQ   128 f32
#define SM_T2  (SM_Q + 512)           // sT2  512 f32 = 2048
#define SM_SZ  (SM_T2 + 2048)         // = 76288 B -> 2 blocks/CU

__global__ __launch_bounds__(256, 2)
void main_dist(const bf16* __restrict__ zbf, const bf16* __restrict__ basesT,
               const bf16* __restrict__ G, const float* __restrict__ m_c,
               const float* __restrict__ cur_vars, const float* __restrict__ old_vars,
               const float* __restrict__ znorm, const float* __restrict__ zdotmu,
               const float* __restrict__ munorm, float* __restrict__ gdist)
{
    const int mt = blockIdx.x, c = blockIdx.y;
    const int b0 = mt * 128;
    const float* vars = (c < C_NEW) ? cur_vars + (size_t)c * (R_N + 1)
                                    : old_vars + (size_t)(c - C_NEW) * (R_N + 1);
    __shared__ __align__(16) unsigned char smem[SM_SZ];
    bf16*  sA   = (bf16*)(smem + SM_A);
    bf16*  sB   = (bf16*)(smem + SM_B);
    bf16*  sG   = (bf16*)(smem + SM_G);
    bf16*  sC   = (bf16*)(smem + SM_C);
    float* sM   = (float*)(smem + SM_M);
    float* sInv = (float*)(smem + SM_INV);
    float* sPar = (float*)(smem + SM_PAR);
    float* sCn  = (float*)(smem + SM_CN);
    float* sQ   = (float*)(smem + SM_Q);
    float* sT2  = (float*)(smem + SM_T2);

    const int tid = threadIdx.x, wave = tid >> 6, lane = tid & 63;
    const int quad = lane >> 4, l15 = lane & 15;
    const int wr = (wave >> 1) * 64, wc = (wave & 1) * 64;

    if (tid < 128) {
        sM[tid]   = m_c[c * R_N + tid];
        sInv[tid] = 1.0f / fmaxf(vars[tid], VAR_FLOOR_F);
        sQ[tid]   = 0.0f;
    }

    // ---- GEMM1: coeff_raw = z_tile * B_c  (M=128,N=128,K=768) ----
    f32x4 acc1[4][4];
    #pragma unroll
    for (int i = 0; i < 4; ++i)
        #pragma unroll
        for (int j = 0; j < 4; ++j) acc1[i][j] = (f32x4)0.0f;

    const bf16* Az = zbf + (size_t)b0 * D_N;
    const bf16* Bb = basesT + (size_t)c * R_N * D_N;
    for (int k0 = 0; k0 < D_N; k0 += 64) {
        __syncthreads();
        #pragma unroll
        for (int p = 0; p < 4; ++p) {
            int q = p * 256 + tid, row = q >> 3, u = q & 7;
            *(uint4*)(sA + row * 72 + u * 8) = *(const uint4*)(Az + (size_t)row * D_N + k0 + u * 8);
            *(uint4*)(sB + row * 72 + u * 8) = *(const uint4*)(Bb + (size_t)row * D_N + k0 + u * 8);
        }
        __syncthreads();
        #pragma unroll
        for (int kk = 0; kk < 64; kk += 32) {
            bf16x8 af[4], bg[4];
            #pragma unroll
            for (int i = 0; i < 4; ++i) af[i] = *(const bf16x8*)(sA + (wr + 16 * i + l15) * 72 + kk + quad * 8);
            #pragma unroll
            for (int j = 0; j < 4; ++j) bg[j] = *(const bf16x8*)(sB + (wc + 16 * j + l15) * 72 + kk + quad * 8);
            #pragma unroll
            for (int i = 0; i < 4; ++i)
                #pragma unroll
                for (int j = 0; j < 4; ++j)
                    acc1[i][j] = __builtin_amdgcn_mfma_f32_16x16x32_bf16(af[i], bg[j], acc1[i][j], 0, 0, 0);
        }
    }

    // ---- subtract m_c; keep f32 in regs; write bf16 coeff to sC ----
    #pragma unroll
    for (int j = 0; j < 4; ++j) {
        float mcv = sM[wc + 16 * j + l15];
        #pragma unroll
        for (int i = 0; i < 4; ++i)
            #pragma unroll
            for (int reg = 0; reg < 4; ++reg) {
                float cv = acc1[i][j][reg] - mcv;
                acc1[i][j][reg] = cv;
                int row = wr + 16 * i + quad * 4 + reg;
                int col = wc + 16 * j + l15;
                sC[row * PADC + col] = (bf16)cv;
            }
    }
    __syncthreads();

    // ---- par / cnorm per row (from bf16 coeff) + stage G into sG ----
    {
        int row = tid >> 1, half = tid & 1;
        float par = 0.f, cn = 0.f;
        #pragma unroll
        for (int m = 0; m < 8; ++m) {
            bf16x8 v = *(const bf16x8*)(sC + row * PADC + half * 64 + m * 8);
            #pragma unroll
            for (int e = 0; e < 8; ++e) {
                float f = (float)v[e];
                int col = half * 64 + m * 8 + e;
                cn  += f * f;
                par += f * f * sInv[col];
            }
        }
        sT2[tid] = par;
        sT2[256 + tid] = cn;
    }
    #pragma unroll
    for (int p = 0; p < 8; ++p) {
        int q = p * 256 + tid, s = q >> 4, u = q & 15;
        *(uint4*)(sG + s * PADC + u * 8) = *(const uint4*)(G + (size_t)c * 16384 + (size_t)s * 128 + u * 8);
    }
    __syncthreads();
    if (tid < 128) {
        sPar[tid] = sT2[tid * 2] + sT2[tid * 2 + 1];
        sCn[tid]  = sT2[256 + tid * 2] + sT2[256 + tid * 2 + 1];
    }

    // ---- GEMM2: H = coeff * G  (K=128) ----
    f32x4 acc2[4][4];
    #pragma unroll
    for (int i = 0; i < 4; ++i)
        #pragma unroll
        for (int j = 0; j < 4; ++j) acc2[i][j] = (f32x4)0.0f;
    #pragma unroll
    for (int kc = 0; kc < 128; kc += 32) {
        bf16x8 af[4], bg[4];
        #pragma unroll
        for (int i = 0; i < 4; ++i) af[i] = *(const bf16x8*)(sC + (wr + 16 * i + l15) * PADC + kc + quad * 8);
        #pragma unroll
        for (int j = 0; j < 4; ++j) bg[j] = *(const bf16x8*)(sG + (wc + 16 * j + l15) * PADC + kc + quad * 8);
        #pragma unroll
        for (int i = 0; i < 4; ++i)
            #pragma unroll
            for (int j = 0; j < 4; ++j)
                acc2[i][j] = __builtin_amdgcn_mfma_f32_16x16x32_bf16(af[i], bg[j], acc2[i][j], 0, 0, 0);
    }

    // ---- qsum[row] = sum_s H[row][s] * coeff[row][s] ----
    #pragma unroll
    for (int i = 0; i < 4; ++i)
        #pragma unroll
        for (int reg = 0; reg < 4; ++reg) {
            float qp = 0.f;
            #pragma unroll
            for (int j = 0; j < 4; ++j) qp += acc2[i][j][reg] * acc1[i][j][reg];
            qp += __shfl_xor(qp, 1, 64);
            qp += __shfl_xor(qp, 2, 64);
            qp += __shfl_xor(qp, 4, 64);
            qp += __shfl_xor(qp, 8, 64);
            if (l15 == 0) atomicAdd(&sQ[wr + 16 * i + quad * 4 + reg], qp);
        }
    __syncthreads();

    // ---- final dist per row ----
    if (tid < 128) {
        int b = b0 + tid;
        float nd2 = znorm[b] - 2.0f * zdotmu[b * C_TOT + c] + munorm[c];
        float res = fmaxf(vars[R_N], VAR_FLOOR_F);
        float dist = (sPar[tid] + (nd2 - 2.0f * sCn[tid] + sQ[tid]) / res) / (float)D_N;
        if (!isfinite(dist)) dist = BIG_F;
        gdist[(size_t)b * C_TOT + c] = dist;
    }
}

// ---------------------------------------------------------------------------
// finalize: old_min, masked per-class means, hinge, valid-avg. 1 block.
// ---------------------------------------------------------------------------
__global__ __launch_bounds__(256)
void finalize_kernel(const float* __restrict__ gdist,
                     const int* __restrict__ labels,
                     const int* __restrict__ ncid,
                     float* __restrict__ out)
{
    __shared__ float sOldMin[B_N];
    __shared__ float sCnt[C_NEW], sTot[C_NEW], sOwn[C_NEW], sOld[C_NEW];
    const int tid = threadIdx.x;
    if (tid < C_NEW) { sCnt[tid] = 0.f; sTot[tid] = 0.f; sOwn[tid] = 0.f; sOld[tid] = 0.f; }
    __syncthreads();
    for (int b = tid; b < B_N; b += 256) {
        float mn = 3.4e38f;
        const float* row = gdist + (size_t)b * C_TOT;
        for (int cc = C_NEW; cc < C_TOT; ++cc) mn = fminf(mn, row[cc]);
        sOldMin[b] = mn;
    }
    __syncthreads();
    for (int b = tid; b < B_N; b += 256) {
        int lab = labels[b];
        float om = sOldMin[b];
        for (int k = 0; k < C_NEW; ++k) {
            if (lab == ncid[k]) {
                int col = min(max(ncid[k], 0), C_TOT - 1);
                float ow = gdist[(size_t)b * C_TOT + col];
                atomicAdd(&sCnt[k], 1.0f);
                atomicAdd(&sTot[k], fmaxf(0.0f, MARGIN_F + ow - om));
                atomicAdd(&sOwn[k], ow);
                atomicAdd(&sOld[k], om);
            }
        }
    }
    __syncthreads();
    if (tid == 0) {
        float total = 0.f, own = 0.f, old = 0.f, nv = 0.f;
        for (int k = 0; k < C_NEW; ++k) {
            float cnt = sCnt[k];
            float den = fmaxf(cnt, 1.0f);
            if (cnt > 0.f) {
                nv += 1.f;
                total += sTot[k] / den;
                own   += sOwn[k] / den;
                old   += sOld[k] / den;
            }
        }
        float nvd = fmaxf(nv, 1.0f);
        out[0] = total / nvd;
        out[1] = own / nvd;
        out[2] = old / nvd;
    }
}

// ---------------------------------------------------------------------------
// workspace layout (bytes, all 256-aligned):
//   gdist   @ 0         : 512*110*4      = 225280
//   zbf     @ 225280    : 512*768*2      = 786432
//   znorm   @ 1011712   : 512*4          = 2048
//   zdotmu  @ 1013760   : 512*110*4      = 225280
//   munorm  @ 1239040   : 110*4          -> 512
//   m_c     @ 1239552   : 110*128*4      = 56320
//   basesT  @ 1295872   : 110*128*768*2  = 21626880
//   G       @ 22922752  : 110*128*128*2  = 3604480
//   total ~26.5 MB
// ---------------------------------------------------------------------------
extern "C" void kernel_launch(void* const* d_in, const int* in_sizes, int n_in,
                              void* d_out, int out_size, void* d_ws, size_t ws_size,
                              hipStream_t stream)
{
    const float* features  = (const float*)d_in[0];
    const int*   labels    = (const int*)d_in[1];
    const int*   ncid      = (const int*)d_in[2];
    const float* cur_means = (const float*)d_in[3];
    const float* cur_bases = (const float*)d_in[4];
    const float* cur_vars  = (const float*)d_in[5];
    const float* old_means = (const float*)d_in[6];
    const float* old_bases = (const float*)d_in[7];
    const float* old_vars  = (const float*)d_in[8];

    unsigned char* ws = (unsigned char*)d_ws;
    float* gdist  = (float*)(ws + 0);
    bf16*  zbf    = (bf16*) (ws + 225280);
    float* znorm  = (float*)(ws + 1011712);
    float* zdotmu = (float*)(ws + 1013760);
    float* munorm = (float*)(ws + 1239040);
    float* m_c    = (float*)(ws + 1239552);
    bf16*  basesT = (bf16*) (ws + 1295872);
    bf16*  G      = (bf16*) (ws + 22922752);

    hipMemsetAsync(m_c, 0, (size_t)C_TOT * R_N * sizeof(float), stream);

    prep_z<<<dim3(128), dim3(256), 0, stream>>>(features, cur_means, old_means,
                                                zbf, znorm, zdotmu);
    prep_munorm<<<dim3(C_TOT), dim3(256), 0, stream>>>(cur_means, old_means, munorm);
    transpose_mc<<<dim3(6, C_TOT), dim3(256), 0, stream>>>(cur_bases, old_bases,
                                                           cur_means, old_means,
                                                           basesT, m_c);
    gram<<<dim3(C_TOT), dim3(256), 0, stream>>>(basesT, G);
    main_dist<<<dim3(4, C_TOT), dim3(256), 0, stream>>>(zbf, basesT, G, m_c,
                                                        cur_vars, old_vars,
                                                        znorm, zdotmu, munorm, gdist);
    finalize_kernel<<<dim3(1), dim3(256), 0, stream>>>(gdist, labels, ncid, (float*)d_out);
}

// Round 3
// 202.031 us; speedup vs baseline: 4.5725x; 1.3239x over previous
//
#include <hip/hip_runtime.h>
#include <hip/hip_bf16.h>
#include <math.h>
#include <stdint.h>

#define B_N   512
#define D_N   768
#define R_N   128
#define C_NEW 10
#define C_OLD 100
#define C_TOT 110
#define MARGIN_F    5.0f
#define VAR_FLOOR_F 1e-4f
#define BIG_F       1e6f

typedef __bf16 bf16;
typedef __bf16 bf16x4 __attribute__((ext_vector_type(4)));
typedef __bf16 bf16x8 __attribute__((ext_vector_type(8)));
typedef float  f32x4  __attribute__((ext_vector_type(4)));

__device__ __forceinline__ float cleanf(float v) { return isfinite(v) ? v : 0.0f; }

// ---------------------------------------------------------------------------
// prep_z: clean z -> bf16 copy + znorm[b]. grid 128, block 256 (wave per row).
// ---------------------------------------------------------------------------
__global__ __launch_bounds__(256)
void prep_z(const float* __restrict__ z, bf16* __restrict__ zbf, float* __restrict__ znorm)
{
    const int wave = threadIdx.x >> 6, lane = threadIdx.x & 63;
    const int b = blockIdx.x * 4 + wave;
    const float4* src = (const float4*)(z + (size_t)b * D_N);
    bf16x4* dst = (bf16x4*)(zbf + (size_t)b * D_N);
    float nrm = 0.f;
    #pragma unroll
    for (int i = 0; i < 3; ++i) {
        float4 v = src[lane + i * 64];
        v.x = cleanf(v.x); v.y = cleanf(v.y); v.z = cleanf(v.z); v.w = cleanf(v.w);
        nrm += v.x * v.x + v.y * v.y + v.z * v.z + v.w * v.w;
        bf16x4 w;
        w[0] = (bf16)v.x; w[1] = (bf16)v.y; w[2] = (bf16)v.z; w[3] = (bf16)v.w;
        dst[lane + i * 64] = w;
    }
    #pragma unroll
    for (int off = 32; off >= 1; off >>= 1) nrm += __shfl_xor(nrm, off, 64);
    if (lane == 0) znorm[b] = nrm;
}

// ---------------------------------------------------------------------------
// prep_munorm: munorm[c] = ||mu_c||^2. grid 110, block 256.
// ---------------------------------------------------------------------------
__global__ __launch_bounds__(256)
void prep_munorm(const float* __restrict__ cur_means, const float* __restrict__ old_means,
                 float* __restrict__ munorm)
{
    const int c = blockIdx.x;
    const float* mu = (c < C_NEW) ? cur_means + (size_t)c * D_N
                                  : old_means + (size_t)(c - C_NEW) * D_N;
    float p = 0.f;
    for (int d = threadIdx.x; d < D_N; d += 256) p += mu[d] * mu[d];
    #pragma unroll
    for (int off = 32; off >= 1; off >>= 1) p += __shfl_xor(p, off, 64);
    __shared__ float s[4];
    const int wave = threadIdx.x >> 6, lane = threadIdx.x & 63;
    if (lane == 0) s[wave] = p;
    __syncthreads();
    if (threadIdx.x == 0) munorm[c] = s[0] + s[1] + s[2] + s[3];
}

// ---------------------------------------------------------------------------
// transpose_mc: basesT[c][r][d] (bf16) from bases[c][d][r] (f32), plus
// m_c[c][r] += sum_d mu[d]*B[d][r] (atomic, m_c pre-zeroed).
// grid (6, 110), block 256. Tile: 128 d x 128 r.
// ---------------------------------------------------------------------------
__global__ __launch_bounds__(256)
void transpose_mc(const float* __restrict__ cur_bases, const float* __restrict__ old_bases,
                  const float* __restrict__ cur_means, const float* __restrict__ old_means,
                  bf16* __restrict__ basesT, float* __restrict__ m_c)
{
    const int dt = blockIdx.x, c = blockIdx.y;
    const float* Bc = (c < C_NEW) ? cur_bases + (size_t)c * D_N * R_N
                                  : old_bases + (size_t)(c - C_NEW) * D_N * R_N;
    const float* mu = (c < C_NEW) ? cur_means + (size_t)c * D_N
                                  : old_means + (size_t)(c - C_NEW) * D_N;
    __shared__ bf16 T[128][132];
    __shared__ float sMu[128];
    const int t = threadIdx.x;
    const int d0 = dt * 128;
    if (t < 128) sMu[t] = mu[d0 + t];

    #pragma unroll 4
    for (int it = 0; it < 16; ++it) {
        int q = it * 256 + t;
        int d = q >> 5, rr = (q & 31) * 4;
        float4 v = *(const float4*)(Bc + (size_t)(d0 + d) * R_N + rr);
        T[rr + 0][d] = (bf16)v.x;
        T[rr + 1][d] = (bf16)v.y;
        T[rr + 2][d] = (bf16)v.z;
        T[rr + 3][d] = (bf16)v.w;
    }
    __syncthreads();

    #pragma unroll 4
    for (int it = 0; it < 16; ++it) {
        int q = it * 256 + t;
        int r = q >> 5, dd = (q & 31) * 4;
        ushort4 w = *(const ushort4*)&T[r][dd];
        *(ushort4*)(basesT + (size_t)c * R_N * D_N + (size_t)r * D_N + d0 + dd) = w;
    }

    {
        int r = t & 127, dh = t >> 7;
        float p = 0.f;
        #pragma unroll 8
        for (int k = 0; k < 64; ++k) {
            int d = dh * 64 + k;
            p += sMu[d] * (float)T[r][d];
        }
        atomicAdd(&m_c[c * R_N + r], p);
    }
}

// ---------------------------------------------------------------------------
// gram: G[c] = B_c^T B_c in bf16 from basesT. grid 110, block 256.
// ---------------------------------------------------------------------------
__global__ __launch_bounds__(256)
void gram(const bf16* __restrict__ basesT, bf16* __restrict__ G)
{
    const int c = blockIdx.x;
    const bf16* Tc = basesT + (size_t)c * R_N * D_N;
    __shared__ bf16 sT[128][72];
    const int tid = threadIdx.x, wave = tid >> 6, lane = tid & 63;
    const int quad = lane >> 4, l15 = lane & 15;
    const int wr = (wave >> 1) * 64, wc = (wave & 1) * 64;

    f32x4 acc[4][4];
    #pragma unroll
    for (int i = 0; i < 4; ++i)
        #pragma unroll
        for (int j = 0; j < 4; ++j) acc[i][j] = (f32x4)0.0f;

    for (int k0 = 0; k0 < D_N; k0 += 64) {
        __syncthreads();
        #pragma unroll
        for (int p = 0; p < 4; ++p) {
            int q = p * 256 + tid, row = q >> 3, u = q & 7;
            *(uint4*)(&sT[row][u * 8]) = *(const uint4*)(Tc + (size_t)row * D_N + k0 + u * 8);
        }
        __syncthreads();
        #pragma unroll
        for (int kk = 0; kk < 64; kk += 32) {
            bf16x8 af[4], bg[4];
            #pragma unroll
            for (int i = 0; i < 4; ++i) af[i] = *(const bf16x8*)(&sT[wr + 16 * i + l15][kk + quad * 8]);
            #pragma unroll
            for (int j = 0; j < 4; ++j) bg[j] = *(const bf16x8*)(&sT[wc + 16 * j + l15][kk + quad * 8]);
            #pragma unroll
            for (int i = 0; i < 4; ++i)
                #pragma unroll
                for (int j = 0; j < 4; ++j)
                    acc[i][j] = __builtin_amdgcn_mfma_f32_16x16x32_bf16(af[i], bg[j], acc[i][j], 0, 0, 0);
        }
    }
    #pragma unroll
    for (int i = 0; i < 4; ++i)
        #pragma unroll
        for (int j = 0; j < 4; ++j)
            #pragma unroll
            for (int reg = 0; reg < 4; ++reg) {
                int r = wr + 16 * i + quad * 4 + reg;
                int s = wc + 16 * j + l15;
                G[(size_t)c * 16384 + (size_t)r * 128 + s] = (bf16)acc[i][j][reg];
            }
}

// ---------------------------------------------------------------------------
// main_dist: coeff = z*B - m_c (MFMA), par/cnorm, zdot (VALU, co-issued),
// H = coeff*G (MFMA), qsum, dist. grid (4, 110), block 256.
// ---------------------------------------------------------------------------
#define PADC 136
#define SM_A   0
#define SM_B   18432
#define SM_G   0
#define SM_C   36864
#define SM_M   (36864 + 34816)        // 71680
#define SM_INV (SM_M + 512)           // 72192
#define SM_PAR (SM_INV + 512)         // 72704
#define SM_CN  (SM_PAR + 512)         // 73216
#define SM_Q   (SM_CN + 512)          // 73728
#define SM_T2  (SM_Q + 512)           // 74240 : 768 f32 (par|cn|zdot)
#define SM_MU  (SM_T2 + 3072)         // 77312 : 768 bf16
#define SM_SZ  (SM_MU + 1536)         // 78848 B -> 2 blocks/CU (157.7/160 KB)

__global__ __launch_bounds__(256, 2)
void main_dist(const bf16* __restrict__ zbf, const bf16* __restrict__ basesT,
               const bf16* __restrict__ G, const float* __restrict__ m_c,
               const float* __restrict__ cur_vars, const float* __restrict__ old_vars,
               const float* __restrict__ cur_means, const float* __restrict__ old_means,
               const float* __restrict__ znorm, const float* __restrict__ munorm,
               float* __restrict__ gdist)
{
    const int mt = blockIdx.x, c = blockIdx.y;
    const int b0 = mt * 128;
    const float* vars = (c < C_NEW) ? cur_vars + (size_t)c * (R_N + 1)
                                    : old_vars + (size_t)(c - C_NEW) * (R_N + 1);
    const float* mu = (c < C_NEW) ? cur_means + (size_t)c * D_N
                                  : old_means + (size_t)(c - C_NEW) * D_N;
    __shared__ __align__(16) unsigned char smem[SM_SZ];
    bf16*  sA   = (bf16*)(smem + SM_A);
    bf16*  sB   = (bf16*)(smem + SM_B);
    bf16*  sG   = (bf16*)(smem + SM_G);
    bf16*  sC   = (bf16*)(smem + SM_C);
    float* sM   = (float*)(smem + SM_M);
    float* sInv = (float*)(smem + SM_INV);
    float* sPar = (float*)(smem + SM_PAR);
    float* sCn  = (float*)(smem + SM_CN);
    float* sQ   = (float*)(smem + SM_Q);
    float* sT2  = (float*)(smem + SM_T2);
    bf16*  sMuB = (bf16*)(smem + SM_MU);

    const int tid = threadIdx.x, wave = tid >> 6, lane = tid & 63;
    const int quad = lane >> 4, l15 = lane & 15;
    const int wr = (wave >> 1) * 64, wc = (wave & 1) * 64;

    if (tid < 128) {
        sM[tid]   = m_c[c * R_N + tid];
        sInv[tid] = 1.0f / fmaxf(vars[tid], VAR_FLOOR_F);
        sQ[tid]   = 0.0f;
    }
    for (int i = tid; i < D_N; i += 256) sMuB[i] = (bf16)mu[i];

    // ---- GEMM1: coeff_raw = z_tile * B_c ; zdot via VALU alongside ----
    f32x4 acc1[4][4];
    #pragma unroll
    for (int i = 0; i < 4; ++i)
        #pragma unroll
        for (int j = 0; j < 4; ++j) acc1[i][j] = (f32x4)0.0f;
    float zd = 0.f;
    const int zrow = tid >> 1, zhalf = tid & 1;

    const bf16* Az = zbf + (size_t)b0 * D_N;
    const bf16* Bb = basesT + (size_t)c * R_N * D_N;
    for (int k0 = 0; k0 < D_N; k0 += 64) {
        __syncthreads();
        #pragma unroll
        for (int p = 0; p < 4; ++p) {
            int q = p * 256 + tid, row = q >> 3, u = q & 7;
            *(uint4*)(sA + row * 72 + u * 8) = *(const uint4*)(Az + (size_t)row * D_N + k0 + u * 8);
            *(uint4*)(sB + row * 72 + u * 8) = *(const uint4*)(Bb + (size_t)row * D_N + k0 + u * 8);
        }
        __syncthreads();
        #pragma unroll
        for (int kk = 0; kk < 64; kk += 32) {
            bf16x8 af[4], bg[4];
            #pragma unroll
            for (int i = 0; i < 4; ++i) af[i] = *(const bf16x8*)(sA + (wr + 16 * i + l15) * 72 + kk + quad * 8);
            #pragma unroll
            for (int j = 0; j < 4; ++j) bg[j] = *(const bf16x8*)(sB + (wc + 16 * j + l15) * 72 + kk + quad * 8);
            #pragma unroll
            for (int i = 0; i < 4; ++i)
                #pragma unroll
                for (int j = 0; j < 4; ++j)
                    acc1[i][j] = __builtin_amdgcn_mfma_f32_16x16x32_bf16(af[i], bg[j], acc1[i][j], 0, 0, 0);
        }
        // zdot partial: row zrow, k-half zhalf of this 64-chunk
        {
            const bf16* zr = sA + zrow * 72 + zhalf * 32;
            const bf16* mr = sMuB + k0 + zhalf * 32;
            #pragma unroll
            for (int m = 0; m < 4; ++m) {
                bf16x8 a = *(const bf16x8*)(zr + m * 8);
                bf16x8 b = *(const bf16x8*)(mr + m * 8);
                #pragma unroll
                for (int e = 0; e < 8; ++e) zd += (float)a[e] * (float)b[e];
            }
        }
    }
    sT2[512 + tid] = zd;

    // ---- subtract m_c; keep f32 in regs; write bf16 coeff to sC ----
    #pragma unroll
    for (int j = 0; j < 4; ++j) {
        float mcv = sM[wc + 16 * j + l15];
        #pragma unroll
        for (int i = 0; i < 4; ++i)
            #pragma unroll
            for (int reg = 0; reg < 4; ++reg) {
                float cv = acc1[i][j][reg] - mcv;
                acc1[i][j][reg] = cv;
                int row = wr + 16 * i + quad * 4 + reg;
                int col = wc + 16 * j + l15;
                sC[row * PADC + col] = (bf16)cv;
            }
    }
    __syncthreads();

    // ---- par / cnorm per row (from bf16 coeff) + stage G into sG ----
    {
        int row = tid >> 1, half = tid & 1;
        float par = 0.f, cn = 0.f;
        #pragma unroll
        for (int m = 0; m < 8; ++m) {
            bf16x8 v = *(const bf16x8*)(sC + row * PADC + half * 64 + m * 8);
            #pragma unroll
            for (int e = 0; e < 8; ++e) {
                float f = (float)v[e];
                int col = half * 64 + m * 8 + e;
                cn  += f * f;
                par += f * f * sInv[col];
            }
        }
        sT2[tid] = par;
        sT2[256 + tid] = cn;
    }
    #pragma unroll
    for (int p = 0; p < 8; ++p) {
        int q = p * 256 + tid, s = q >> 4, u = q & 15;
        *(uint4*)(sG + s * PADC + u * 8) = *(const uint4*)(G + (size_t)c * 16384 + (size_t)s * 128 + u * 8);
    }
    __syncthreads();
    if (tid < 128) {
        sPar[tid] = sT2[tid * 2] + sT2[tid * 2 + 1];
        sCn[tid]  = sT2[256 + tid * 2] + sT2[256 + tid * 2 + 1];
    }

    // ---- GEMM2: H = coeff * G  (K=128) ----
    f32x4 acc2[4][4];
    #pragma unroll
    for (int i = 0; i < 4; ++i)
        #pragma unroll
        for (int j = 0; j < 4; ++j) acc2[i][j] = (f32x4)0.0f;
    #pragma unroll
    for (int kc = 0; kc < 128; kc += 32) {
        bf16x8 af[4], bg[4];
        #pragma unroll
        for (int i = 0; i < 4; ++i) af[i] = *(const bf16x8*)(sC + (wr + 16 * i + l15) * PADC + kc + quad * 8);
        #pragma unroll
        for (int j = 0; j < 4; ++j) bg[j] = *(const bf16x8*)(sG + (wc + 16 * j + l15) * PADC + kc + quad * 8);
        #pragma unroll
        for (int i = 0; i < 4; ++i)
            #pragma unroll
            for (int j = 0; j < 4; ++j)
                acc2[i][j] = __builtin_amdgcn_mfma_f32_16x16x32_bf16(af[i], bg[j], acc2[i][j], 0, 0, 0);
    }

    // ---- qsum[row] = sum_s H[row][s] * coeff[row][s] ----
    #pragma unroll
    for (int i = 0; i < 4; ++i)
        #pragma unroll
        for (int reg = 0; reg < 4; ++reg) {
            float qp = 0.f;
            #pragma unroll
            for (int j = 0; j < 4; ++j) qp += acc2[i][j][reg] * acc1[i][j][reg];
            qp += __shfl_xor(qp, 1, 64);
            qp += __shfl_xor(qp, 2, 64);
            qp += __shfl_xor(qp, 4, 64);
            qp += __shfl_xor(qp, 8, 64);
            if (l15 == 0) atomicAdd(&sQ[wr + 16 * i + quad * 4 + reg], qp);
        }
    __syncthreads();

    // ---- final dist per row ----
    if (tid < 128) {
        int b = b0 + tid;
        float zdot = sT2[512 + tid * 2] + sT2[512 + tid * 2 + 1];
        float nd2 = znorm[b] - 2.0f * zdot + munorm[c];
        float res = fmaxf(vars[R_N], VAR_FLOOR_F);
        float dist = (sPar[tid] + (nd2 - 2.0f * sCn[tid] + sQ[tid]) / res) / (float)D_N;
        if (!isfinite(dist)) dist = BIG_F;
        gdist[(size_t)b * C_TOT + c] = dist;
    }
}

// ---------------------------------------------------------------------------
// finalize: old_min, masked per-class means, hinge, valid-avg. 1 block.
// ---------------------------------------------------------------------------
__global__ __launch_bounds__(256)
void finalize_kernel(const float* __restrict__ gdist,
                     const int* __restrict__ labels,
                     const int* __restrict__ ncid,
                     float* __restrict__ out)
{
    __shared__ float sOldMin[B_N];
    __shared__ float sCnt[C_NEW], sTot[C_NEW], sOwn[C_NEW], sOld[C_NEW];
    const int tid = threadIdx.x;
    if (tid < C_NEW) { sCnt[tid] = 0.f; sTot[tid] = 0.f; sOwn[tid] = 0.f; sOld[tid] = 0.f; }
    __syncthreads();
    for (int b = tid; b < B_N; b += 256) {
        float mn = 3.4e38f;
        const float* row = gdist + (size_t)b * C_TOT;
        for (int cc = C_NEW; cc < C_TOT; ++cc) mn = fminf(mn, row[cc]);
        sOldMin[b] = mn;
    }
    __syncthreads();
    for (int b = tid; b < B_N; b += 256) {
        int lab = labels[b];
        float om = sOldMin[b];
        for (int k = 0; k < C_NEW; ++k) {
            if (lab == ncid[k]) {
                int col = min(max(ncid[k], 0), C_TOT - 1);
                float ow = gdist[(size_t)b * C_TOT + col];
                atomicAdd(&sCnt[k], 1.0f);
                atomicAdd(&sTot[k], fmaxf(0.0f, MARGIN_F + ow - om));
                atomicAdd(&sOwn[k], ow);
                atomicAdd(&sOld[k], om);
            }
        }
    }
    __syncthreads();
    if (tid == 0) {
        float total = 0.f, own = 0.f, old = 0.f, nv = 0.f;
        for (int k = 0; k < C_NEW; ++k) {
            float cnt = sCnt[k];
            float den = fmaxf(cnt, 1.0f);
            if (cnt > 0.f) {
                nv += 1.f;
                total += sTot[k] / den;
                own   += sOwn[k] / den;
                old   += sOld[k] / den;
            }
        }
        float nvd = fmaxf(nv, 1.0f);
        out[0] = total / nvd;
        out[1] = own / nvd;
        out[2] = old / nvd;
    }
}

// ---------------------------------------------------------------------------
// workspace layout (bytes):
//   gdist  @ 0        : 225280
//   zbf    @ 225280   : 786432
//   znorm  @ 1011712  : 2048
//   munorm @ 1013760  : 512
//   m_c    @ 1014272  : 56320
//   basesT @ 1070592  : 21626880
//   G      @ 22697472 : 3604480   -> total ~26.3 MB
// ---------------------------------------------------------------------------
extern "C" void kernel_launch(void* const* d_in, const int* in_sizes, int n_in,
                              void* d_out, int out_size, void* d_ws, size_t ws_size,
                              hipStream_t stream)
{
    const float* features  = (const float*)d_in[0];
    const int*   labels    = (const int*)d_in[1];
    const int*   ncid      = (const int*)d_in[2];
    const float* cur_means = (const float*)d_in[3];
    const float* cur_bases = (const float*)d_in[4];
    const float* cur_vars  = (const float*)d_in[5];
    const float* old_means = (const float*)d_in[6];
    const float* old_bases = (const float*)d_in[7];
    const float* old_vars  = (const float*)d_in[8];

    unsigned char* ws = (unsigned char*)d_ws;
    float* gdist  = (float*)(ws + 0);
    bf16*  zbf    = (bf16*) (ws + 225280);
    float* znorm  = (float*)(ws + 1011712);
    float* munorm = (float*)(ws + 1013760);
    float* m_c    = (float*)(ws + 1014272);
    bf16*  basesT = (bf16*) (ws + 1070592);
    bf16*  G      = (bf16*) (ws + 22697472);

    hipMemsetAsync(m_c, 0, (size_t)C_TOT * R_N * sizeof(float), stream);

    prep_z<<<dim3(128), dim3(256), 0, stream>>>(features, zbf, znorm);
    prep_munorm<<<dim3(C_TOT), dim3(256), 0, stream>>>(cur_means, old_means, munorm);
    transpose_mc<<<dim3(6, C_TOT), dim3(256), 0, stream>>>(cur_bases, old_bases,
                                                           cur_means, old_means,
                                                           basesT, m_c);
    gram<<<dim3(C_TOT), dim3(256), 0, stream>>>(basesT, G);
    main_dist<<<dim3(4, C_TOT), dim3(256), 0, stream>>>(zbf, basesT, G, m_c,
                                                        cur_vars, old_vars,
                                                        cur_means, old_means,
                                                        znorm, munorm, gdist);
    finalize_kernel<<<dim3(1), dim3(256), 0, stream>>>(gdist, labels, ncid, (float*)d_out);
}

// Round 4
// 163.843 us; speedup vs baseline: 5.6383x; 1.2331x over previous
//
#include <hip/hip_runtime.h>
#include <hip/hip_bf16.h>
#include <math.h>
#include <stdint.h>

#define B_N   512
#define D_N   768
#define R_N   128
#define C_NEW 10
#define C_OLD 100
#define C_TOT 110
#define MARGIN_F    5.0f
#define VAR_FLOOR_F 1e-4f
#define BIG_F       1e6f

typedef __bf16 bf16;
typedef __bf16 bf16x4 __attribute__((ext_vector_type(4)));
typedef __bf16 bf16x8 __attribute__((ext_vector_type(8)));
typedef float  f32x4  __attribute__((ext_vector_type(4)));

__device__ __forceinline__ float cleanf(float v) { return isfinite(v) ? v : 0.0f; }

// ---------------------------------------------------------------------------
// prep_z: clean z -> bf16 copy + znorm[b]. grid 128, block 256 (wave per row).
// ---------------------------------------------------------------------------
__global__ __launch_bounds__(256)
void prep_z(const float* __restrict__ z, bf16* __restrict__ zbf, float* __restrict__ znorm)
{
    const int wave = threadIdx.x >> 6, lane = threadIdx.x & 63;
    const int b = blockIdx.x * 4 + wave;
    const float4* src = (const float4*)(z + (size_t)b * D_N);
    bf16x4* dst = (bf16x4*)(zbf + (size_t)b * D_N);
    float nrm = 0.f;
    #pragma unroll
    for (int i = 0; i < 3; ++i) {
        float4 v = src[lane + i * 64];
        v.x = cleanf(v.x); v.y = cleanf(v.y); v.z = cleanf(v.z); v.w = cleanf(v.w);
        nrm += v.x * v.x + v.y * v.y + v.z * v.z + v.w * v.w;
        bf16x4 w;
        w[0] = (bf16)v.x; w[1] = (bf16)v.y; w[2] = (bf16)v.z; w[3] = (bf16)v.w;
        dst[lane + i * 64] = w;
    }
    #pragma unroll
    for (int off = 32; off >= 1; off >>= 1) nrm += __shfl_xor(nrm, off, 64);
    if (lane == 0) znorm[b] = nrm;
}

// ---------------------------------------------------------------------------
// prep_munorm: munorm[c] = ||mu_c||^2. grid 110, block 256.
// ---------------------------------------------------------------------------
__global__ __launch_bounds__(256)
void prep_munorm(const float* __restrict__ cur_means, const float* __restrict__ old_means,
                 float* __restrict__ munorm)
{
    const int c = blockIdx.x;
    const float* mu = (c < C_NEW) ? cur_means + (size_t)c * D_N
                                  : old_means + (size_t)(c - C_NEW) * D_N;
    float p = 0.f;
    for (int d = threadIdx.x; d < D_N; d += 256) p += mu[d] * mu[d];
    #pragma unroll
    for (int off = 32; off >= 1; off >>= 1) p += __shfl_xor(p, off, 64);
    __shared__ float s[4];
    const int wave = threadIdx.x >> 6, lane = threadIdx.x & 63;
    if (lane == 0) s[wave] = p;
    __syncthreads();
    if (threadIdx.x == 0) munorm[c] = s[0] + s[1] + s[2] + s[3];
}

// ---------------------------------------------------------------------------
// transpose_mc: basesT[c][r][d] (bf16) from bases[c][d][r] (f32), plus
// m_c[c][r] += sum_d mu[d]*B[d][r] (atomic, m_c pre-zeroed).
// grid (6, 110), block 256. Tile: 128 d x 128 r.
// ---------------------------------------------------------------------------
__global__ __launch_bounds__(256)
void transpose_mc(const float* __restrict__ cur_bases, const float* __restrict__ old_bases,
                  const float* __restrict__ cur_means, const float* __restrict__ old_means,
                  bf16* __restrict__ basesT, float* __restrict__ m_c)
{
    const int dt = blockIdx.x, c = blockIdx.y;
    const float* Bc = (c < C_NEW) ? cur_bases + (size_t)c * D_N * R_N
                                  : old_bases + (size_t)(c - C_NEW) * D_N * R_N;
    const float* mu = (c < C_NEW) ? cur_means + (size_t)c * D_N
                                  : old_means + (size_t)(c - C_NEW) * D_N;
    __shared__ bf16 T[128][132];
    __shared__ float sMu[128];
    const int t = threadIdx.x;
    const int d0 = dt * 128;
    if (t < 128) sMu[t] = mu[d0 + t];

    #pragma unroll 4
    for (int it = 0; it < 16; ++it) {
        int q = it * 256 + t;
        int d = q >> 5, rr = (q & 31) * 4;
        float4 v = *(const float4*)(Bc + (size_t)(d0 + d) * R_N + rr);
        T[rr + 0][d] = (bf16)v.x;
        T[rr + 1][d] = (bf16)v.y;
        T[rr + 2][d] = (bf16)v.z;
        T[rr + 3][d] = (bf16)v.w;
    }
    __syncthreads();

    #pragma unroll 4
    for (int it = 0; it < 16; ++it) {
        int q = it * 256 + t;
        int r = q >> 5, dd = (q & 31) * 4;
        ushort4 w = *(const ushort4*)&T[r][dd];
        *(ushort4*)(basesT + (size_t)c * R_N * D_N + (size_t)r * D_N + d0 + dd) = w;
    }

    {
        int r = t & 127, dh = t >> 7;
        float p = 0.f;
        #pragma unroll 8
        for (int k = 0; k < 64; ++k) {
            int d = dh * 64 + k;
            p += sMu[d] * (float)T[r][d];
        }
        atomicAdd(&m_c[c * R_N + r], p);
    }
}

// ---------------------------------------------------------------------------
// gram: G[c] = B_c^T B_c in bf16 from basesT. grid 110, block 256.
// ---------------------------------------------------------------------------
__global__ __launch_bounds__(256)
void gram(const bf16* __restrict__ basesT, bf16* __restrict__ G)
{
    const int c = blockIdx.x;
    const bf16* Tc = basesT + (size_t)c * R_N * D_N;
    __shared__ bf16 sT[128][72];
    const int tid = threadIdx.x, wave = tid >> 6, lane = tid & 63;
    const int quad = lane >> 4, l15 = lane & 15;
    const int wr = (wave >> 1) * 64, wc = (wave & 1) * 64;

    f32x4 acc[4][4];
    #pragma unroll
    for (int i = 0; i < 4; ++i)
        #pragma unroll
        for (int j = 0; j < 4; ++j) acc[i][j] = (f32x4)0.0f;

    for (int k0 = 0; k0 < D_N; k0 += 64) {
        __syncthreads();
        #pragma unroll
        for (int p = 0; p < 4; ++p) {
            int q = p * 256 + tid, row = q >> 3, u = q & 7;
            *(uint4*)(&sT[row][u * 8]) = *(const uint4*)(Tc + (size_t)row * D_N + k0 + u * 8);
        }
        __syncthreads();
        #pragma unroll
        for (int kk = 0; kk < 64; kk += 32) {
            bf16x8 af[4], bg[4];
            #pragma unroll
            for (int i = 0; i < 4; ++i) af[i] = *(const bf16x8*)(&sT[wr + 16 * i + l15][kk + quad * 8]);
            #pragma unroll
            for (int j = 0; j < 4; ++j) bg[j] = *(const bf16x8*)(&sT[wc + 16 * j + l15][kk + quad * 8]);
            #pragma unroll
            for (int i = 0; i < 4; ++i)
                #pragma unroll
                for (int j = 0; j < 4; ++j)
                    acc[i][j] = __builtin_amdgcn_mfma_f32_16x16x32_bf16(af[i], bg[j], acc[i][j], 0, 0, 0);
        }
    }
    #pragma unroll
    for (int i = 0; i < 4; ++i)
        #pragma unroll
        for (int j = 0; j < 4; ++j)
            #pragma unroll
            for (int reg = 0; reg < 4; ++reg) {
                int r = wr + 16 * i + quad * 4 + reg;
                int s = wc + 16 * j + l15;
                G[(size_t)c * 16384 + (size_t)r * 128 + s] = (bf16)acc[i][j][reg];
            }
}

// ---------------------------------------------------------------------------
// main_dist: coeff = z*B - m_c (MFMA), par/cnorm, zdot (VALU, co-issued),
// H = coeff*G (MFMA), qsum, dist. grid (4, 110), block 256.
// ---------------------------------------------------------------------------
#define PADC 136
#define SM_A   0
#define SM_B   18432
#define SM_G   0
#define SM_C   36864
#define SM_M   (36864 + 34816)        // 71680
#define SM_INV (SM_M + 512)           // 72192
#define SM_PAR (SM_INV + 512)         // 72704
#define SM_CN  (SM_PAR + 512)         // 73216
#define SM_Q   (SM_CN + 512)          // 73728
#define SM_T2  (SM_Q + 512)           // 74240 : 768 f32 (par|cn|zdot)
#define SM_MU  (SM_T2 + 3072)         // 77312 : 768 bf16
#define SM_SZ  (SM_MU + 1536)         // 78848 B -> 2 blocks/CU (157.7/160 KB)

__global__ __launch_bounds__(256, 2)
void main_dist(const bf16* __restrict__ zbf, const bf16* __restrict__ basesT,
               const bf16* __restrict__ G, const float* __restrict__ m_c,
               const float* __restrict__ cur_vars, const float* __restrict__ old_vars,
               const float* __restrict__ cur_means, const float* __restrict__ old_means,
               const float* __restrict__ znorm, const float* __restrict__ munorm,
               float* __restrict__ gdist)
{
    const int mt = blockIdx.x, c = blockIdx.y;
    const int b0 = mt * 128;
    const float* vars = (c < C_NEW) ? cur_vars + (size_t)c * (R_N + 1)
                                    : old_vars + (size_t)(c - C_NEW) * (R_N + 1);
    const float* mu = (c < C_NEW) ? cur_means + (size_t)c * D_N
                                  : old_means + (size_t)(c - C_NEW) * D_N;
    __shared__ __align__(16) unsigned char smem[SM_SZ];
    bf16*  sA   = (bf16*)(smem + SM_A);
    bf16*  sB   = (bf16*)(smem + SM_B);
    bf16*  sG   = (bf16*)(smem + SM_G);
    bf16*  sC   = (bf16*)(smem + SM_C);
    float* sM   = (float*)(smem + SM_M);
    float* sInv = (float*)(smem + SM_INV);
    float* sPar = (float*)(smem + SM_PAR);
    float* sCn  = (float*)(smem + SM_CN);
    float* sQ   = (float*)(smem + SM_Q);
    float* sT2  = (float*)(smem + SM_T2);
    bf16*  sMuB = (bf16*)(smem + SM_MU);

    const int tid = threadIdx.x, wave = tid >> 6, lane = tid & 63;
    const int quad = lane >> 4, l15 = lane & 15;
    const int wr = (wave >> 1) * 64, wc = (wave & 1) * 64;

    if (tid < 128) {
        sM[tid]   = m_c[c * R_N + tid];
        sInv[tid] = 1.0f / fmaxf(vars[tid], VAR_FLOOR_F);
        sQ[tid]   = 0.0f;
    }
    for (int i = tid; i < D_N; i += 256) sMuB[i] = (bf16)mu[i];

    // ---- GEMM1: coeff_raw = z_tile * B_c ; zdot via VALU alongside ----
    f32x4 acc1[4][4];
    #pragma unroll
    for (int i = 0; i < 4; ++i)
        #pragma unroll
        for (int j = 0; j < 4; ++j) acc1[i][j] = (f32x4)0.0f;
    float zd = 0.f;
    const int zrow = tid >> 1, zhalf = tid & 1;

    const bf16* Az = zbf + (size_t)b0 * D_N;
    const bf16* Bb = basesT + (size_t)c * R_N * D_N;
    for (int k0 = 0; k0 < D_N; k0 += 64) {
        __syncthreads();
        #pragma unroll
        for (int p = 0; p < 4; ++p) {
            int q = p * 256 + tid, row = q >> 3, u = q & 7;
            *(uint4*)(sA + row * 72 + u * 8) = *(const uint4*)(Az + (size_t)row * D_N + k0 + u * 8);
            *(uint4*)(sB + row * 72 + u * 8) = *(const uint4*)(Bb + (size_t)row * D_N + k0 + u * 8);
        }
        __syncthreads();
        #pragma unroll
        for (int kk = 0; kk < 64; kk += 32) {
            bf16x8 af[4], bg[4];
            #pragma unroll
            for (int i = 0; i < 4; ++i) af[i] = *(const bf16x8*)(sA + (wr + 16 * i + l15) * 72 + kk + quad * 8);
            #pragma unroll
            for (int j = 0; j < 4; ++j) bg[j] = *(const bf16x8*)(sB + (wc + 16 * j + l15) * 72 + kk + quad * 8);
            #pragma unroll
            for (int i = 0; i < 4; ++i)
                #pragma unroll
                for (int j = 0; j < 4; ++j)
                    acc1[i][j] = __builtin_amdgcn_mfma_f32_16x16x32_bf16(af[i], bg[j], acc1[i][j], 0, 0, 0);
        }
        // zdot partial: row zrow, k-half zhalf of this 64-chunk
        {
            const bf16* zr = sA + zrow * 72 + zhalf * 32;
            const bf16* mr = sMuB + k0 + zhalf * 32;
            #pragma unroll
            for (int m = 0; m < 4; ++m) {
                bf16x8 a = *(const bf16x8*)(zr + m * 8);
                bf16x8 b = *(const bf16x8*)(mr + m * 8);
                #pragma unroll
                for (int e = 0; e < 8; ++e) zd += (float)a[e] * (float)b[e];
            }
        }
    }
    sT2[512 + tid] = zd;

    // ---- subtract m_c; keep f32 in regs; write bf16 coeff to sC ----
    #pragma unroll
    for (int j = 0; j < 4; ++j) {
        float mcv = sM[wc + 16 * j + l15];
        #pragma unroll
        for (int i = 0; i < 4; ++i)
            #pragma unroll
            for (int reg = 0; reg < 4; ++reg) {
                float cv = acc1[i][j][reg] - mcv;
                acc1[i][j][reg] = cv;
                int row = wr + 16 * i + quad * 4 + reg;
                int col = wc + 16 * j + l15;
                sC[row * PADC + col] = (bf16)cv;
            }
    }
    __syncthreads();

    // ---- par / cnorm per row (from bf16 coeff) + stage G into sG ----
    {
        int row = tid >> 1, half = tid & 1;
        float par = 0.f, cn = 0.f;
        #pragma unroll
        for (int m = 0; m < 8; ++m) {
            bf16x8 v = *(const bf16x8*)(sC + row * PADC + half * 64 + m * 8);
            #pragma unroll
            for (int e = 0; e < 8; ++e) {
                float f = (float)v[e];
                int col = half * 64 + m * 8 + e;
                cn  += f * f;
                par += f * f * sInv[col];
            }
        }
        sT2[tid] = par;
        sT2[256 + tid] = cn;
    }
    #pragma unroll
    for (int p = 0; p < 8; ++p) {
        int q = p * 256 + tid, s = q >> 4, u = q & 15;
        *(uint4*)(sG + s * PADC + u * 8) = *(const uint4*)(G + (size_t)c * 16384 + (size_t)s * 128 + u * 8);
    }
    __syncthreads();
    if (tid < 128) {
        sPar[tid] = sT2[tid * 2] + sT2[tid * 2 + 1];
        sCn[tid]  = sT2[256 + tid * 2] + sT2[256 + tid * 2 + 1];
    }

    // ---- GEMM2: H = coeff * G  (K=128) ----
    f32x4 acc2[4][4];
    #pragma unroll
    for (int i = 0; i < 4; ++i)
        #pragma unroll
        for (int j = 0; j < 4; ++j) acc2[i][j] = (f32x4)0.0f;
    #pragma unroll
    for (int kc = 0; kc < 128; kc += 32) {
        bf16x8 af[4], bg[4];
        #pragma unroll
        for (int i = 0; i < 4; ++i) af[i] = *(const bf16x8*)(sC + (wr + 16 * i + l15) * PADC + kc + quad * 8);
        #pragma unroll
        for (int j = 0; j < 4; ++j) bg[j] = *(const bf16x8*)(sG + (wc + 16 * j + l15) * PADC + kc + quad * 8);
        #pragma unroll
        for (int i = 0; i < 4; ++i)
            #pragma unroll
            for (int j = 0; j < 4; ++j)
                acc2[i][j] = __builtin_amdgcn_mfma_f32_16x16x32_bf16(af[i], bg[j], acc2[i][j], 0, 0, 0);
    }

    // ---- qsum[row] = sum_s H[row][s] * coeff[row][s] ----
    #pragma unroll
    for (int i = 0; i < 4; ++i)
        #pragma unroll
        for (int reg = 0; reg < 4; ++reg) {
            float qp = 0.f;
            #pragma unroll
            for (int j = 0; j < 4; ++j) qp += acc2[i][j][reg] * acc1[i][j][reg];
            qp += __shfl_xor(qp, 1, 64);
            qp += __shfl_xor(qp, 2, 64);
            qp += __shfl_xor(qp, 4, 64);
            qp += __shfl_xor(qp, 8, 64);
            if (l15 == 0) atomicAdd(&sQ[wr + 16 * i + quad * 4 + reg], qp);
        }
    __syncthreads();

    // ---- final dist per row ----
    if (tid < 128) {
        int b = b0 + tid;
        float zdot = sT2[512 + tid * 2] + sT2[512 + tid * 2 + 1];
        float nd2 = znorm[b] - 2.0f * zdot + munorm[c];
        float res = fmaxf(vars[R_N], VAR_FLOOR_F);
        float dist = (sPar[tid] + (nd2 - 2.0f * sCn[tid] + sQ[tid]) / res) / (float)D_N;
        if (!isfinite(dist)) dist = BIG_F;
        gdist[(size_t)b * C_TOT + c] = dist;
    }
}

// ---------------------------------------------------------------------------
// finalize_stage1: one thread per batch row. Row is contiguous (440 B, L2-hot).
// old_min + own-class lookup in registers, then 4 atomics into acc[k][4].
// grid 8 x 64.
// ---------------------------------------------------------------------------
__global__ __launch_bounds__(64)
void finalize_stage1(const float* __restrict__ gdist,
                     const int* __restrict__ labels,
                     const int* __restrict__ ncid,
                     float* __restrict__ acc)
{
    const int b = blockIdx.x * 64 + threadIdx.x;
    const float* row = gdist + (size_t)b * C_TOT;
    float mn = 3.4e38f;
    #pragma unroll
    for (int cc = C_NEW; cc < C_TOT; ++cc) mn = fminf(mn, row[cc]);
    const int lab = labels[b];
    #pragma unroll
    for (int k = 0; k < C_NEW; ++k) {
        if (lab == ncid[k]) {
            int col = min(max(ncid[k], 0), C_TOT - 1);
            float ow = row[col];
            atomicAdd(&acc[k * 4 + 0], 1.0f);
            atomicAdd(&acc[k * 4 + 1], fmaxf(0.0f, MARGIN_F + ow - mn));
            atomicAdd(&acc[k * 4 + 2], ow);
            atomicAdd(&acc[k * 4 + 3], mn);
        }
    }
}

// ---------------------------------------------------------------------------
// finalize_stage2: fold acc[10][4] -> out[3]. 1 block x 64 (thread 0 works).
// ---------------------------------------------------------------------------
__global__ __launch_bounds__(64)
void finalize_stage2(const float* __restrict__ acc, float* __restrict__ out)
{
    if (threadIdx.x == 0) {
        float total = 0.f, own = 0.f, old = 0.f, nv = 0.f;
        #pragma unroll
        for (int k = 0; k < C_NEW; ++k) {
            float cnt = acc[k * 4 + 0];
            float den = fmaxf(cnt, 1.0f);
            if (cnt > 0.f) {
                nv += 1.f;
                total += acc[k * 4 + 1] / den;
                own   += acc[k * 4 + 2] / den;
                old   += acc[k * 4 + 3] / den;
            }
        }
        float nvd = fmaxf(nv, 1.0f);
        out[0] = total / nvd;
        out[1] = own / nvd;
        out[2] = old / nvd;
    }
}

// ---------------------------------------------------------------------------
// workspace layout (bytes):
//   gdist  @ 0        : 225280
//   zbf    @ 225280   : 786432
//   znorm  @ 1011712  : 2048
//   munorm @ 1013760  : 512
//   m_c    @ 1014272  : 56320
//   acc    @ 1070592  : 256      (zeroed together with m_c)
//   basesT @ 1070848  : 21626880
//   G      @ 22697728 : 3604480  -> total ~26.3 MB
// ---------------------------------------------------------------------------
extern "C" void kernel_launch(void* const* d_in, const int* in_sizes, int n_in,
                              void* d_out, int out_size, void* d_ws, size_t ws_size,
                              hipStream_t stream)
{
    const float* features  = (const float*)d_in[0];
    const int*   labels    = (const int*)d_in[1];
    const int*   ncid      = (const int*)d_in[2];
    const float* cur_means = (const float*)d_in[3];
    const float* cur_bases = (const float*)d_in[4];
    const float* cur_vars  = (const float*)d_in[5];
    const float* old_means = (const float*)d_in[6];
    const float* old_bases = (const float*)d_in[7];
    const float* old_vars  = (const float*)d_in[8];

    unsigned char* ws = (unsigned char*)d_ws;
    float* gdist  = (float*)(ws + 0);
    bf16*  zbf    = (bf16*) (ws + 225280);
    float* znorm  = (float*)(ws + 1011712);
    float* munorm = (float*)(ws + 1013760);
    float* m_c    = (float*)(ws + 1014272);
    float* acc    = (float*)(ws + 1070592);
    bf16*  basesT = (bf16*) (ws + 1070848);
    bf16*  G      = (bf16*) (ws + 22697728);

    hipMemsetAsync(m_c, 0, 56320 + 256, stream);   // m_c + acc

    prep_z<<<dim3(128), dim3(256), 0, stream>>>(features, zbf, znorm);
    prep_munorm<<<dim3(C_TOT), dim3(256), 0, stream>>>(cur_means, old_means, munorm);
    transpose_mc<<<dim3(6, C_TOT), dim3(256), 0, stream>>>(cur_bases, old_bases,
                                                           cur_means, old_means,
                                                           basesT, m_c);
    gram<<<dim3(C_TOT), dim3(256), 0, stream>>>(basesT, G);
    main_dist<<<dim3(4, C_TOT), dim3(256), 0, stream>>>(zbf, basesT, G, m_c,
                                                        cur_vars, old_vars,
                                                        cur_means, old_means,
                                                        znorm, munorm, gdist);
    finalize_stage1<<<dim3(8), dim3(64), 0, stream>>>(gdist, labels, ncid, acc);
    finalize_stage2<<<dim3(1), dim3(64), 0, stream>>>(acc, (float*)d_out);
}